// Round 11
// baseline (45.219 us; speedup 1.0000x reference)
//
#include <hip/hip_runtime.h>
#include <math.h>

#define BB 2
#define NN 1024
#define HH 4
#define F_IN 128
#define HID 32
#define TJ 64
#define NT (NN/TJ)     // 16 j-tiles, one u64 mask word each

#define LOG2E 1.44269504f

typedef unsigned long long u64;

// ---- workspace layout (bytes) ----
#define WS_X    0              // f32 x [bh][n][k]          = 1048576
#define WS_D6   1048576        // f32 [bh][n]               = 32768
#define WS_BITS 1081344        // u64 [b][n][NT]            = 262144

// ---------------- Kernel 1: proj (x=feat@W) + d6 + adjacency bit-pack
// (R10-verbatim except d6 pre-scaled by LOG2E for exp2 in attn)
__global__ __launch_bounds__(128) void gat_proj_kernel(const float* __restrict__ feat,
        const float* __restrict__ W, const float* __restrict__ Wa, const int* __restrict__ adj,
        float* __restrict__ xout, float* __restrict__ d6, u64* __restrict__ bits) {
    const int RPB = 2;
    int blk = blockIdx.x;              // 0 .. BB*NN/2-1
    int b  = blk / (NN / RPB);
    int n0 = (blk % (NN / RPB)) * RPB;
    int t  = threadIdx.x;              // 0..127 -> output column h*32+k

    __shared__ float fs[RPB][F_IN];
    fs[0][t] = feat[((size_t)(b*NN + n0    ))*F_IN + t];
    fs[1][t] = feat[((size_t)(b*NN + n0 + 1))*F_IN + t];
    __syncthreads();

    float a0 = 0.f, a1 = 0.f;
    for (int f = 0; f < F_IN; ++f) {
        float w = W[f*(HH*HID) + t];
        a0 = fmaf(fs[0][f], w, a0);
        a1 = fmaf(fs[1][f], w, a1);
    }
    int h = t >> 5, k = t & 31;
    int bh = b*HH + h;
    xout[((size_t)bh*NN + n0    )*HID + k] = a0;
    xout[((size_t)bh*NN + n0 + 1)*HID + k] = a1;

    float w_t = Wa[t];
    float p0 = a0*w_t, p1 = a1*w_t;
#pragma unroll
    for (int off = 16; off >= 1; off >>= 1) {
        p0 += __shfl_xor(p0, off, 32);
        p1 += __shfl_xor(p1, off, 32);
    }
    if (k == 0) {
        d6[(size_t)bh*NN + n0    ] = 0.6f*LOG2E*p0;
        d6[(size_t)bh*NN + n0 + 1] = 0.6f*LOG2E*p1;
    }
    // adjacency bit-pack for this block's 2 rows
#pragma unroll
    for (int r = 0; r < RPB; ++r) {
        const int* arow = adj + ((size_t)(b*NN + n0 + r))*NN;
        u64* brow = bits + ((size_t)(b*NN + n0 + r))*NT;
#pragma unroll
        for (int c0 = 0; c0 < NN; c0 += 128) {
            u64 m = __ballot(arow[c0 + t] > 0);
            if ((t & 63) == 0) brow[(c0 + t) >> 6] = m;
        }
    }
}

__device__ __forceinline__ float sload(float v) {
    return __uint_as_float(__builtin_amdgcn_readfirstlane(__float_as_uint(v)));
}

// ---------------- Kernel 2: fused attention. 512 thr (8 waves), ONE query row per wave.
// R10-verbatim structure; changes: xi/wa4/ci scalarized to SGPRs (readfirstlane),
// mask applied as SGPR-pair cndmask (1 inst), exp2 instead of expf.
__global__ __launch_bounds__(512) void gat_attn6_kernel(const float* __restrict__ x,
                                                        const float* __restrict__ d6,
                                                        const u64* __restrict__ bits,
                                                        const float* __restrict__ Wa,
                                                        float* __restrict__ out) {
    const int tid = threadIdx.x;
    const int w = __builtin_amdgcn_readfirstlane(tid >> 6);   // wave id 0..7
    const int l = tid & 63;
    const int blk = blockIdx.x;                // 0..1023
    const int bh = blk >> 7;                   // 128 blocks per (b,h)
    const int i0 = (blk & 127) << 3;           // 8 rows per block
    const int h = bh & (HH - 1), b = bh >> 2;
    const int i = i0 + w;                      // this wave's query row (uniform)

    const float* xbh = x  + (size_t)bh * NN * HID;
    const float* dbh = d6 + (size_t)bh * NN;
    const u64* brow = bits + ((size_t)b*NN + i) * NT;

    // wave-uniform row data -> SGPRs (forces VGPR footprint down, +2 waves/SIMD)
    float xi[HID], wa4[HID];
#pragma unroll
    for (int k = 0; k < HID; ++k) {
        xi[k]  = sload(xbh[(size_t)i*HID + k]);
        wa4[k] = sload((0.4f * LOG2E) * Wa[h*HID + k]);
    }
    float ci = sload(dbh[i]);

    __shared__ float xs[2][TJ][36];     // 18.4 KB, pad 36 -> conflict-free b128

    float acc[HID];
#pragma unroll
    for (int k = 0; k < HID; ++k) acc[k] = 0.f;
    float lsum = 0.f;

    // staging: tile = 64 rows x 32 floats = 512 float4; 512 threads x 1
    const int r0 = tid >> 3, q0 = (tid & 7) << 2;
    const float4* gsrc = (const float4*)xbh;
    float4 pre = gsrc[tid];             // prefetch tile 0

    for (int t = 0; t < NT; ++t) {
        const int bc = t & 1;
        *(float4*)&xs[bc][r0][q0] = pre;
        __syncthreads();
        if (t + 1 < NT) pre = gsrc[(t + 1)*512 + tid];

        u64 wM = brow[t];               // uniform -> SGPR pair
        float dj = dbh[t*TJ + l];

        float4 xj4[8];
#pragma unroll
        for (int q = 0; q < 8; ++q) xj4[q] = *(const float4*)&xs[bc][l][4*q];

        // e = log2e*( 0.6*(d_i+d_j) + sum_k 0.4*wa_k*|x_i+x_j| )   (folded into consts)
        float s0 = 0.f, s1 = 0.f, s2 = 0.f, s3 = 0.f;
#pragma unroll
        for (int q = 0; q < 8; ++q) {
            float4 xv = xj4[q];
            float v;
            v = xi[4*q+0] + xv.x; s0 = fmaf(wa4[4*q+0], fabsf(v), s0);
            v = xi[4*q+1] + xv.y; s1 = fmaf(wa4[4*q+1], fabsf(v), s1);
            v = xi[4*q+2] + xv.z; s2 = fmaf(wa4[4*q+2], fabsf(v), s2);
            v = xi[4*q+3] + xv.w; s3 = fmaf(wa4[4*q+3], fabsf(v), s3);
        }
        float e = (ci + dj) + ((s0 + s1) + (s2 + s3));
        float pe = exp2f(e);            // bare v_exp_f32 (log2e pre-folded)
        float p;
        // mask word IS a 64-lane predicate: one VOP3 cndmask with SGPR-pair mask
        asm("v_cndmask_b32 %0, 0, %1, %2" : "=v"(p) : "v"(pe), "s"(wM));
        lsum += p;
#pragma unroll
        for (int q = 0; q < 8; ++q) {
            float4 xv = xj4[q];
            acc[4*q+0] = fmaf(p, xv.x, acc[4*q+0]);
            acc[4*q+1] = fmaf(p, xv.y, acc[4*q+1]);
            acc[4*q+2] = fmaf(p, xv.z, acc[4*q+2]);
            acc[4*q+3] = fmaf(p, xv.w, acc[4*q+3]);
        }
    }

    // ---- epilogue (R10-verbatim): fold upper 32 lanes, butterfly denominator,
    // per-wave 32x33 transpose-reduce reusing xs (2 rounds of 4 regions).
#pragma unroll
    for (int k = 0; k < HID; ++k) acc[k] += __shfl_xor(acc[k], 32, 64);
#pragma unroll
    for (int off = 32; off >= 1; off >>= 1) lsum += __shfl_xor(lsum, off, 64);
    float inv = 1.0f / lsum;
    float* orow = out + ((size_t)(b*NN + i))*(HH*HID) + h*HID;

    __syncthreads();                       // all tile reads done; xs reusable
    float* xsf = (float*)xs;               // 4 regions x 1056 floats
    float* sw = xsf + (w & 3) * (32*33);
    if (w < 4) {
        if (l < 32) {
#pragma unroll
            for (int k = 0; k < HID; ++k) sw[k*33 + l] = acc[k];
        }
        if (l < 32) {
            float res = 0.f;
#pragma unroll
            for (int m = 0; m < 32; ++m) res += sw[l*33 + m];
            orow[l] = res * inv;
        }
    }
    __syncthreads();
    if (w >= 4) {
        if (l < 32) {
#pragma unroll
            for (int k = 0; k < HID; ++k) sw[k*33 + l] = acc[k];
        }
        if (l < 32) {
            float res = 0.f;
#pragma unroll
            for (int m = 0; m < 32; ++m) res += sw[l*33 + m];
            orow[l] = res * inv;
        }
    }
}

extern "C" void kernel_launch(void* const* d_in, const int* in_sizes, int n_in,
                              void* d_out, int out_size, void* d_ws, size_t ws_size,
                              hipStream_t stream) {
    const float* node_feat = (const float*)d_in[0];
    const int*   adj_mtx   = (const int*)d_in[1];
    const float* W         = (const float*)d_in[2];
    const float* Wa        = (const float*)d_in[3];
    float* out = (float*)d_out;

    char* ws = (char*)d_ws;
    float* x_ws  = (float*)(ws + WS_X);
    float* d6_ws = (float*)(ws + WS_D6);
    u64*   bits  = (u64*)(ws + WS_BITS);

    hipLaunchKernelGGL(gat_proj_kernel, dim3(BB*NN/2), dim3(128), 0, stream,
                       node_feat, W, Wa, adj_mtx, x_ws, d6_ws, bits);
    hipLaunchKernelGGL(gat_attn6_kernel, dim3(BB*HH*NN/8), dim3(512), 0, stream,
                       x_ws, d6_ws, bits, Wa, out);
}